// Round 12
// baseline (459.570 us; speedup 1.0000x reference)
//
#include <hip/hip_runtime.h>
#include <hip/hip_bf16.h>
#include <cmath>

#define T_STEPS 16
#define BATCH   512
#define N_IN    3072
#define S1      256
#define S2      256
#define S3      128
#define NEXP    8
#define M_ROWS  (T_STEPS * BATCH)   // 8192
#define MT_ALL  (M_ROWS / 32)       // 256 m-tiles

typedef int v4i  __attribute__((ext_vector_type(4)));
typedef int v16i __attribute__((ext_vector_type(16)));
typedef unsigned long long u64;
typedef unsigned int uint32;

// ---------------------------------------------------------------------------
// bit->byte unpack: 16 bits -> 16 i8 (0/1). mul-free spread.
// ---------------------------------------------------------------------------
__device__ __forceinline__ v4i unpack16_bits(uint32 w16)
{
    v4i d;
    #pragma unroll
    for (int c = 0; c < 4; ++c) {
        uint32 x = (w16 >> (4 * c)) & 0xFu;
        x = x + (x << 7);
        x = x + (x << 14);
        d[c] = (int)(x & 0x01010101u);
    }
    return d;
}

// ---------------------------------------------------------------------------
// 4-limb weight digitize (stages 2/3). B-row gr = o*32 + e*4 + limb.
// ---------------------------------------------------------------------------
template<int S, int K>
__device__ __forceinline__ void digitize_chunk(
    const float* __restrict__ W, char* __restrict__ Bf, int t)
{
    int lane16 = t & 63;
    int o  = (t >> 6) & (S - 1);
    int kb = t >> ((S == 256) ? 14 : 13);
    int r  = lane16 & 31;
    int qd = lane16 >> 5;
    int e    = r >> 2;
    int limb = r & 3;
    int k0 = kb * 32 + qd * 16;

    const float4* Wp = (const float4*)(W + ((size_t)e * S + o) * K + k0);
    char out[16];
    #pragma unroll
    for (int f4 = 0; f4 < 4; ++f4) {
        float4 w = Wp[f4];
        float ws[4] = {w.x, w.y, w.z, w.w};
        #pragma unroll
        for (int c = 0; c < 4; ++c) {
            long long q = llrint((double)ws[c] * 4294967296.0);
            int d = 0;
            #pragma unroll
            for (int l = 0; l < 4; ++l) {
                int dl = (int)((q + 128) & 255) - 128;
                q = (q - dl) >> 8;
                if (l == limb) d = dl;
            }
            out[f4 * 4 + c] = (char)d;
        }
    }
    *(v4i*)(Bf + (size_t)t * 16) = *(v4i*)out;
}

// ---------------------------------------------------------------------------
// prep: pack x bits + 3-limb LIMB-MAJOR digitize W1 + 4-limb W2/W3.
// W1 rows gr = limb*2048 + (o*8+e): the 3 limbs of one (o,e) occupy the same
// column position in 3 different n-tiles (jj = limb) -> per-lane recombine.
// ---------------------------------------------------------------------------
__global__ __launch_bounds__(256) void prep(
    const float* __restrict__ x,  const float* __restrict__ W1,
    const float* __restrict__ W2, const float* __restrict__ W3,
    u64* __restrict__ bitsT, char* __restrict__ B1f,
    char* __restrict__ B2f,  char* __restrict__ B3f)
{
    const int bid = blockIdx.x;
    const int tid = threadIdx.x;
    if (bid < 98304) {
        int gid = bid * 256 + tid;
        float v = x[gid];
        u64 m = __ballot(v >= 0.5f);
        if ((tid & 63) == 0) {
            int tb = gid / N_IN;                 // t*512 + b
            int k  = gid - tb * N_IN;
            int t  = tb >> 9;
            int b  = tb & 511;
            bitsT[(size_t)(k >> 6) * M_ROWS + (b * 16 + t)] = m;
        }
    } else if (bid < 98304 + 4608) {
        // W1 3-limb limb-major: chunks = 96 kb * 192 tiles * 64 l16
        int t    = (bid - 98304) * 256 + tid;
        int l16  = t & 63;
        int tt   = t >> 6;               // kb*192 + tile
        int tile = tt % 192;
        int kb   = tt / 192;
        int gr   = tile * 32 + (l16 & 31);
        int qd   = l16 >> 5;
        int limb = gr >> 11;             // 0..2
        int oe   = gr & 2047;
        int o    = oe >> 3;
        int e    = oe & 7;
        int k0   = kb * 32 + qd * 16;
        const float4* Wp = (const float4*)(W1 + ((size_t)e * S1 + o) * N_IN + k0);
        char out[16];
        #pragma unroll
        for (int f4 = 0; f4 < 4; ++f4) {
            float4 w = Wp[f4];
            float ws[4] = {w.x, w.y, w.z, w.w};
            #pragma unroll
            for (int c = 0; c < 4; ++c) {
                long long q = llrint((double)ws[c] * 16777216.0);
                int d0 = (int)((q + 128) & 255) - 128;
                long long q1 = (q - d0) >> 8;
                int d1 = (int)((q1 + 128) & 255) - 128;
                int d2 = (int)((q1 - d1) >> 8);
                int d  = (limb == 0) ? d0 : ((limb == 1) ? d1 : d2);
                out[f4 * 4 + c] = (char)d;
            }
        }
        *(v4i*)(B1f + (size_t)t * 16) = *(v4i*)out;
    } else if (bid < 98304 + 4608 + 512) {
        digitize_chunk<S2, S1>(W2, B2f, (bid - 98304 - 4608) * 256 + tid);
    } else {
        digitize_chunk<S3, S2>(W3, B3f, (bid - 98304 - 4608 - 512) * 256 + tid);
    }
}

// ---------------------------------------------------------------------------
// R12 stage 1: LDS-staged B, 32m x 96n wave tile, 4 blocks/CU.
// R10 proved LDS staging breaks the VMEM plateau (218->155, Mfma 32->45%);
// remaining gap is occupancy (172 unified regs -> 2 blocks/CU; bubbles
// uncovered). R11's VGPR micro-shave failed (76->76). R12 shrinks the
// ACCUMULATOR instead: 32m x 96n -> acc = 48 AGPR + ~60 VGPR = ~108 unified
// -> 4 waves/SIMD = 4 independent blocks/CU whose barrier phases interleave.
// A-bits back in registers (2 u64/buf; R11's A-LDS round trip cost 6us).
// Per-CU per-phase: MFMA 1757 cy/SIMD > LDS-read 1536 > VMEM 1024 -> MFMA-
// bound. Counted vmcnt(5) (3 B-lds + 2 A in flight), raw barriers, setprio.
// Not R4's 32m failure mode: B latency is LDS-hidden, TLP = 4 async blocks.
// ---------------------------------------------------------------------------
__global__ __launch_bounds__(256, 4) void fused_stage1(
    const u64* __restrict__ AT0, const char* __restrict__ Bf,
    const float* __restrict__ g, char* __restrict__ Cf,
    float* __restrict__ Mean)
{
    constexpr int NGR = (N_IN / 32) / 4;     // 24 granules of 4 kb
    __shared__ char smem[32768];
    double* hs  = (double*)smem;             // [128][32], epilogue only
    char*  Blds = smem;                      // [2][12][1024] B staging

    const int tid  = threadIdx.x;
    const int lane = tid & 63;
    const int w    = tid >> 6;
    const int col  = lane & 31;
    const int qd   = lane >> 5;
    const int sh16 = qd * 16;

    // mblk-major XCD map: 64 nblk (8/XCD), 64 mblk
    const int id    = blockIdx.x;
    const int xcd   = id & 7;
    const int inner = id >> 3;
    const int nblk  = xcd * 8 + (inner >> 6);
    const int mblk  = inner & 63;
    const int m0    = mblk * 128;

    // A: wave w owns rows m0 + w*32 + col (both qd halves load same row,
    // use their 16-bit subword via sh16)
    const u64* AT = AT0 + (m0 + w * 32 + col);

    // B staging: wave w stages kb-slot w of each granule, jj = 0..2.
    const char* Bsrc = Bf + (size_t)nblk * 1024 + lane * 16;
    char* Bdst0 = Blds + (w * 3) * 1024 + lane * 16;

    v16i acc[3];
    #pragma unroll
    for (int jj = 0; jj < 3; ++jj)
        #pragma unroll
        for (int r = 0; r < 16; ++r) acc[jj][r] = 0;

    u64 a0[2], a1[2];                        // [buf]: kw0, kw1

    auto stageB = [&](int gr, int buf) {
        const char* src = Bsrc + (size_t)(gr * 4 + w) * (192 * 1024);
        char* dst = Bdst0 + buf * 12288;
        #pragma unroll
        for (int jj = 0; jj < 3; ++jj)
            __builtin_amdgcn_global_load_lds(
                (const __attribute__((address_space(1))) uint32*)(src + jj * 65536),
                (__attribute__((address_space(3))) uint32*)(dst + jj * 1024),
                16, 0, 0);
    };
    auto loadA = [&](int gr, int buf) {
        a0[buf] = AT[(size_t)(gr * 2 + 0) * M_ROWS];
        a1[buf] = AT[(size_t)(gr * 2 + 1) * M_ROWS];
    };

    // prologue: granule 0 in flight (5 loads per wave)
    stageB(0, 0);
    loadA(0, 0);

    auto iter = [&](int gr, int cur, int pf) {
        stageB(gr + 1, pf);                  // clamp-free: buffers padded
        loadA(gr + 1, pf);
        asm volatile("s_waitcnt vmcnt(5)" ::: "memory");
        __builtin_amdgcn_sched_barrier(0);
        __builtin_amdgcn_s_barrier();        // buf[cur] staged for all waves
        const char* bb = Blds + cur * 12288 + lane * 16;
        __builtin_amdgcn_s_setprio(1);
        #pragma unroll
        for (int kbl = 0; kbl < 4; ++kbl) {
            v4i Bfr[3];
            #pragma unroll
            for (int jj = 0; jj < 3; ++jj)
                Bfr[jj] = *(const v4i*)(bb + (kbl * 3 + jj) * 1024);
            u64 a = (kbl >> 1) ? a1[cur] : a0[cur];
            uint32 dw = (kbl & 1) ? (uint32)(a >> 32) : (uint32)a;
            v4i af = unpack16_bits(dw >> sh16);
            #pragma unroll
            for (int jj = 0; jj < 3; ++jj)
                acc[jj] = __builtin_amdgcn_mfma_i32_32x32x32_i8(
                    af, Bfr[jj], acc[jj], 0, 0, 0);
        }
        __builtin_amdgcn_s_setprio(0);
        __builtin_amdgcn_s_barrier();        // all waves done with buf[cur]
    };

    for (int gp = 0; gp < NGR; gp += 2) {
        iter(gp + 0, 0, 1);
        iter(gp + 1, 1, 0);
    }

    // ---- epilogue: per-lane exact recombine -> hs (aliases staging LDS) ----
    const double sc = 1.0 / 16777216.0;
    __syncthreads();
    #pragma unroll
    for (int reg = 0; reg < 16; ++reg) {
        int r  = w * 32 + (reg & 3) + 8 * (reg >> 2) + 4 * qd;
        int lo = acc[0][reg] + (acc[1][reg] << 8);
        double d = ((double)lo + 65536.0 * (double)acc[2][reg]) * sc;
        hs[r * 32 + col] = d;
    }
    __syncthreads();

    // ---- LIF: thread = (b_loc = tid>>5, oe = tid&31), single pass ----
    const int b_loc = tid >> 5;
    const int oe    = tid & 31;
    const int o_loc = oe >> 3;
    const int e     = tid & 7;
    const float ge  = g[e];
    const int bg    = mblk * 8 + b_loc;
    const int og    = nblk * 4 + o_loc;
    const int kb_a   = og >> 5;
    const int qd_a   = (og >> 4) & 1;
    const int byte_a = og & 15;

    double v = 0.0;
    float gacc = 0.0f;
    #pragma unroll
    for (int t = 0; t < T_STEPS; ++t) {
        double h  = hs[(b_loc * 16 + t) * 32 + oe];
        double vv = v * 0.95 + h;
        int spk = (vv >= 1.0) ? 1 : 0;
        v = vv - (double)spk;
        float gs = ge * (float)spk;
        gs += __shfl_xor(gs, 1);
        gs += __shfl_xor(gs, 2);
        gs += __shfl_xor(gs, 4);
        gacc += gs;
        int cnt = spk;
        cnt += __shfl_xor(cnt, 1);
        cnt += __shfl_xor(cnt, 2);
        cnt += __shfl_xor(cnt, 4);
        if (e == 0) {
            int mp = bg * 16 + t;
            int lane_a = (mp & 31) + 32 * qd_a;
            Cf[(((size_t)kb_a * MT_ALL + (mp >> 5)) * 64 + lane_a) * 16 + byte_a]
                = (char)cnt;
        }
    }
    if (e == 0) Mean[(size_t)bg * S1 + og] = gacc * 0.0625f;
}

// ---------------------------------------------------------------------------
// Generic fused stage (stages 2/3): R6/R9's proven frag path, 4-limb, block
// 256m x 64n, shuffle recombine epilogue. Unchanged.
// ---------------------------------------------------------------------------
template<int K, int S, int SHIFT, bool WRITEC, int NBLK, int MINW>
__global__ __launch_bounds__(256, MINW) void fused_stage(
    const char* __restrict__ Ap, const char* __restrict__ Bf,
    const float* __restrict__ g, char* __restrict__ Cf,
    float* __restrict__ Mean)
{
    constexpr int KI = K / 64;
    static_assert(KI % 2 == 0, "frag path wants even KI");
    constexpr int NT = S;
    constexpr int NS = NBLK / 8;
    __shared__ double hs[256][16];           // 32 KB

    const int tid  = threadIdx.x;
    const int lane = tid & 63;
    const int w    = tid >> 6;
    const int col  = lane & 31;
    const int qd   = lane >> 5;
    const int wm   = w * 64;

    const int id    = blockIdx.x;
    const int xcd   = id & 7;
    const int inner = id >> 3;
    const int nblk  = xcd * NS + (inner >> 5);
    const int mblk  = inner & 31;
    const int m0    = mblk * 256;

    const int nt0 = nblk * 2;
    const char* Bbase = Bf + ((size_t)nt0 * 64 + lane) * 16;

    v16i acc[2][2];
    #pragma unroll
    for (int i = 0; i < 2; ++i)
        #pragma unroll
        for (int j = 0; j < 2; ++j)
            #pragma unroll
            for (int r = 0; r < 16; ++r) acc[i][j][r] = 0;

    auto loadB = [&](int kb, int jj) -> v4i {
        return *(const v4i*)(Bbase + (size_t)kb * (NT * 1024) + jj * 1024);
    };
    const int mt0 = (m0 + wm) >> 5;
    const char* Abase = Ap + ((size_t)mt0 * 64 + lane) * 16;
    auto loadA = [&](int kb, int ii) -> v4i {
        return *(const v4i*)(Abase + (size_t)kb * (MT_ALL * 1024) + ii * 1024);
    };

    v4i Ab[2][4];
    v4i Bb[2][4];

    #pragma unroll
    for (int ks = 0; ks < 2; ++ks) {
        Ab[0][ks * 2 + 0] = loadA(ks, 0);
        Ab[0][ks * 2 + 1] = loadA(ks, 1);
        #pragma unroll
        for (int jj = 0; jj < 2; ++jj)
            Bb[0][ks * 2 + jj] = loadB(ks, jj);
    }

    auto body = [&](int it, int cur, int pf) {
        const int itp = it + 1;
        #pragma unroll
        for (int ks = 0; ks < 2; ++ks) {
            Ab[pf][ks * 2 + 0] = loadA(itp * 2 + ks, 0);
            Ab[pf][ks * 2 + 1] = loadA(itp * 2 + ks, 1);
            #pragma unroll
            for (int jj = 0; jj < 2; ++jj)
                Bb[pf][ks * 2 + jj] = loadB(itp * 2 + ks, jj);
        }
        #pragma unroll
        for (int ks = 0; ks < 2; ++ks)
            #pragma unroll
            for (int jj = 0; jj < 2; ++jj) {
                acc[0][jj] = __builtin_amdgcn_mfma_i32_32x32x32_i8(Ab[cur][ks*2+0], Bb[cur][ks*2+jj], acc[0][jj], 0,0,0);
                acc[1][jj] = __builtin_amdgcn_mfma_i32_32x32x32_i8(Ab[cur][ks*2+1], Bb[cur][ks*2+jj], acc[1][jj], 0,0,0);
            }
    };
    for (int it = 0; it < KI; it += 2) {
        body(it + 0, 0, 1);
        body(it + 1, 1, 0);
    }

    // ---- limb recombine (exact): int pair-combine then one f64 fma ----
    const double sbase = 1.0 / (double)(1ll << SHIFT);
    #pragma unroll
    for (int j = 0; j < 2; ++j) {
        const int oe = j * 8 + (col >> 2);
        #pragma unroll
        for (int i = 0; i < 2; ++i) {
            #pragma unroll
            for (int reg = 0; reg < 16; ++reg) {
                int a = acc[i][j][reg];
                int s01 = a + (__shfl_xor(a, 1) << 8);
                int s23 = __shfl_xor(s01, 2);
                double d = ((double)s01 + 65536.0 * (double)s23) * sbase;
                if ((col & 3) == 0) {
                    int m = wm + i * 32 + (reg & 3) + 8 * (reg >> 2) + 4 * qd;
                    hs[m][oe] = d;
                }
            }
        }
    }
    __syncthreads();

    const int b_loc  = tid >> 4;
    const int o_loc  = (tid >> 3) & 1;
    const int e      = tid & 7;
    const int oe     = o_loc * 8 + e;
    const float ge   = g[e];
    const int bg = mblk * 16 + b_loc;
    const int og = nblk * 2 + o_loc;

    const int kb_a   = og >> 5;
    const int qd_a   = (og >> 4) & 1;
    const int byte_a = og & 15;

    double v = 0.0;
    float gacc = 0.0f;
    #pragma unroll
    for (int t = 0; t < T_STEPS; ++t) {
        double h  = hs[b_loc * 16 + t][oe];
        double vv = v * 0.95 + h;
        int spk = (vv >= 1.0) ? 1 : 0;
        v = vv - (double)spk;
        float gs = ge * (float)spk;
        gs += __shfl_xor(gs, 1);
        gs += __shfl_xor(gs, 2);
        gs += __shfl_xor(gs, 4);
        gacc += gs;
        if (WRITEC) {
            int cnt = spk;
            cnt += __shfl_xor(cnt, 1);
            cnt += __shfl_xor(cnt, 2);
            cnt += __shfl_xor(cnt, 4);
            if (e == 0) {
                int mp = bg * 16 + t;
                int lane_a = (mp & 31) + 32 * qd_a;
                Cf[(((size_t)kb_a * MT_ALL + (mp >> 5)) * 64 + lane_a) * 16 + byte_a]
                    = (char)cnt;
            }
        }
    }
    if (e == 0) Mean[(size_t)bg * S + og] = gacc * 0.0625f;
}

// ---------------------------------------------------------------------------
// ws layout (bytes), padded for clamp-free prefetch/staging:
//   AbitsT @ 0          : 3 MB  (region 4 MB; A loads reach kw 49 = 3.27 MB)
//   B1f    @ 4194304    : 18 MB 3-limb limb-major (staging reaches kb 99 =
//                          19.6 MB <= region 20.97 MB)
//   B2f    @ 25165824   :  2 MB (region 3 MB >= 2.5 needed)
//   B3f    @ 28311552   :  1 MB (region 2 MB >= 1.3 needed)
//   c1f    @ 30408704   :  2 MB (region 4 MB >= 2.75 needed)
//   c2f    @ 34603008   :  2 MB (region 4 MB)   -> end 38797312 (37 MB)
// ---------------------------------------------------------------------------
extern "C" void kernel_launch(void* const* d_in, const int* in_sizes, int n_in,
                              void* d_out, int out_size, void* d_ws, size_t ws_size,
                              hipStream_t stream) {
    const float* x  = (const float*)d_in[0];
    const float* W1 = (const float*)d_in[1];
    const float* W2 = (const float*)d_in[2];
    const float* W3 = (const float*)d_in[3];
    const float* g1 = (const float*)d_in[4];
    const float* g2 = (const float*)d_in[5];
    const float* g3 = (const float*)d_in[6];
    float* out = (float*)d_out;

    char* ws = (char*)d_ws;
    u64*  AbitsT = (u64*)ws;
    char* B1f    = ws + 4194304ull;
    char* B2f    = ws + 25165824ull;
    char* B3f    = ws + 28311552ull;
    char* c1f    = ws + 30408704ull;
    char* c2f    = ws + 34603008ull;

    dim3 blk(256);

    // --- single precompute dispatch ---
    prep<<<98304 + 4608 + 512 + 256, blk, 0, stream>>>(
        x, W1, W2, W3, AbitsT, B1f, B2f, B3f);

    // --- stage 1: LDS-staged B, 32m x 96n waves, 64 mblk * 64 nblk ---
    fused_stage1<<<64 * 64, blk, 0, stream>>>(AbitsT, B1f, g1, c1f, out);

    // --- stages 2/3: proven 4-limb frag path ---
    fused_stage<S1, S2, 35, true,  128, 3><<<32 * 128, blk, 0, stream>>>(
        c1f, B2f, g2, c2f, out + BATCH * S1);
    fused_stage<S2, S3, 35, false, 64, 3><<<32 * 64, blk, 0, stream>>>(
        c2f, B3f, g3, nullptr, out + BATCH * (S1 + S2));
}

// Round 13
// 444.847 us; speedup vs baseline: 1.0331x; 1.0331x over previous
//
#include <hip/hip_runtime.h>
#include <hip/hip_bf16.h>
#include <cmath>

#define T_STEPS 16
#define BATCH   512
#define N_IN    3072
#define S1      256
#define S2      256
#define S3      128
#define NEXP    8
#define M_ROWS  (T_STEPS * BATCH)   // 8192
#define MT_ALL  (M_ROWS / 32)       // 256 m-tiles

typedef int v4i  __attribute__((ext_vector_type(4)));
typedef int v16i __attribute__((ext_vector_type(16)));
typedef unsigned long long u64;
typedef unsigned int uint32;

// ---------------------------------------------------------------------------
// bit->byte unpack: 16 bits -> 16 i8 (0/1). mul-free spread.
// ---------------------------------------------------------------------------
__device__ __forceinline__ v4i unpack16_bits(uint32 w16)
{
    v4i d;
    #pragma unroll
    for (int c = 0; c < 4; ++c) {
        uint32 x = (w16 >> (4 * c)) & 0xFu;
        x = x + (x << 7);
        x = x + (x << 14);
        d[c] = (int)(x & 0x01010101u);
    }
    return d;
}

// ---------------------------------------------------------------------------
// 4-limb weight digitize (stages 2/3). B-row gr = o*32 + e*4 + limb.
// ---------------------------------------------------------------------------
template<int S, int K>
__device__ __forceinline__ void digitize_chunk(
    const float* __restrict__ W, char* __restrict__ Bf, int t)
{
    int lane16 = t & 63;
    int o  = (t >> 6) & (S - 1);
    int kb = t >> ((S == 256) ? 14 : 13);
    int r  = lane16 & 31;
    int qd = lane16 >> 5;
    int e    = r >> 2;
    int limb = r & 3;
    int k0 = kb * 32 + qd * 16;

    const float4* Wp = (const float4*)(W + ((size_t)e * S + o) * K + k0);
    char out[16];
    #pragma unroll
    for (int f4 = 0; f4 < 4; ++f4) {
        float4 w = Wp[f4];
        float ws[4] = {w.x, w.y, w.z, w.w};
        #pragma unroll
        for (int c = 0; c < 4; ++c) {
            long long q = llrint((double)ws[c] * 4294967296.0);
            int d = 0;
            #pragma unroll
            for (int l = 0; l < 4; ++l) {
                int dl = (int)((q + 128) & 255) - 128;
                q = (q - dl) >> 8;
                if (l == limb) d = dl;
            }
            out[f4 * 4 + c] = (char)d;
        }
    }
    *(v4i*)(Bf + (size_t)t * 16) = *(v4i*)out;
}

// ---------------------------------------------------------------------------
// prep: pack x bits (4 k-words per wave, 24576 blocks) + 3-limb limb-major
// digitize W1 + 4-limb W2/W3. Segments of 1024 elems never cross a tb row
// (3072 = 12*256); each wave packs 4 consecutive 64-bit k-words of one row.
// ---------------------------------------------------------------------------
__global__ __launch_bounds__(256) void prep(
    const float* __restrict__ x,  const float* __restrict__ W1,
    const float* __restrict__ W2, const float* __restrict__ W3,
    u64* __restrict__ bitsT, char* __restrict__ B1f,
    char* __restrict__ B2f,  char* __restrict__ B3f)
{
    const int bid = blockIdx.x;
    const int tid = threadIdx.x;
    if (bid < 24576) {
        int wbase = bid * 1024 + (tid >> 6) * 256;
        int lane  = tid & 63;
        int tb = wbase / N_IN;
        int k0 = wbase - tb * N_IN;
        int t  = tb >> 9;
        int b  = tb & 511;
        int mrow = b * 16 + t;
        #pragma unroll
        for (int c = 0; c < 4; ++c) {
            float v = x[(size_t)wbase + c * 64 + lane];
            u64 m = __ballot(v >= 0.5f);
            if (lane == 0)
                bitsT[(size_t)((k0 + c * 64) >> 6) * M_ROWS + mrow] = m;
        }
    } else if (bid < 24576 + 4608) {
        // W1 3-limb limb-major: chunks = 96 kb * 192 tiles * 64 l16
        int t    = (bid - 24576) * 256 + tid;
        int l16  = t & 63;
        int tt   = t >> 6;               // kb*192 + tile
        int tile = tt % 192;
        int kb   = tt / 192;
        int gr   = tile * 32 + (l16 & 31);
        int qd   = l16 >> 5;
        int limb = gr >> 11;             // 0..2
        int oe   = gr & 2047;
        int o    = oe >> 3;
        int e    = oe & 7;
        int k0   = kb * 32 + qd * 16;
        const float4* Wp = (const float4*)(W1 + ((size_t)e * S1 + o) * N_IN + k0);
        char out[16];
        #pragma unroll
        for (int f4 = 0; f4 < 4; ++f4) {
            float4 w = Wp[f4];
            float ws[4] = {w.x, w.y, w.z, w.w};
            #pragma unroll
            for (int c = 0; c < 4; ++c) {
                long long q = llrint((double)ws[c] * 16777216.0);
                int d0 = (int)((q + 128) & 255) - 128;
                long long q1 = (q - d0) >> 8;
                int d1 = (int)((q1 + 128) & 255) - 128;
                int d2 = (int)((q1 - d1) >> 8);
                int d  = (limb == 0) ? d0 : ((limb == 1) ? d1 : d2);
                out[f4 * 4 + c] = (char)d;
            }
        }
        *(v4i*)(B1f + (size_t)t * 16) = *(v4i*)out;
    } else if (bid < 24576 + 4608 + 512) {
        digitize_chunk<S2, S1>(W2, B2f, (bid - 24576 - 4608) * 256 + tid);
    } else {
        digitize_chunk<S3, S2>(W3, B3f, (bid - 24576 - 4608 - 512) * 256 + tid);
    }
}

// ---------------------------------------------------------------------------
// R13 stage 1: LDS-staged B + 2-deep B-fragment register pipeline.
// R12 post-mortem: occupancy 30->41% changed NOTHING (MfmaUtil pinned 45%).
// VGPR=44 showed the compiler serialized each kbl's ds_read->unpack->MFMA
// chain (~120 cy LDS latency vs ~110 cy MFMA = 50% duty, = the measured
// 45%). R13 forces a rolling 2-deep Bfr[2][3] pipeline: kbl's MFMA cluster
// runs while kbl+2's ds_reads fly. ~116 unified regs, still 4 waves/SIMD.
// Counted vmcnt(5), raw barriers, setprio around the compute cluster.
// ---------------------------------------------------------------------------
__global__ __launch_bounds__(256, 4) void fused_stage1(
    const u64* __restrict__ AT0, const char* __restrict__ Bf,
    const float* __restrict__ g, char* __restrict__ Cf,
    float* __restrict__ Mean)
{
    constexpr int NGR = (N_IN / 32) / 4;     // 24 granules of 4 kb
    __shared__ char smem[32768];
    double* hs  = (double*)smem;             // [128][32], epilogue only
    char*  Blds = smem;                      // [2][12][1024] B staging

    const int tid  = threadIdx.x;
    const int lane = tid & 63;
    const int w    = tid >> 6;
    const int col  = lane & 31;
    const int qd   = lane >> 5;
    const int sh16 = qd * 16;

    // mblk-major XCD map: 64 nblk (8/XCD), 64 mblk
    const int id    = blockIdx.x;
    const int xcd   = id & 7;
    const int inner = id >> 3;
    const int nblk  = xcd * 8 + (inner >> 6);
    const int mblk  = inner & 63;
    const int m0    = mblk * 128;

    // A: wave w owns rows m0 + w*32 + col (qd halves pick 16-bit subword)
    const u64* AT = AT0 + (m0 + w * 32 + col);

    // B staging: wave w stages kb-slot w of each granule, jj = 0..2.
    const char* Bsrc = Bf + (size_t)nblk * 1024 + lane * 16;
    char* Bdst0 = Blds + (w * 3) * 1024 + lane * 16;

    v16i acc[3];
    #pragma unroll
    for (int jj = 0; jj < 3; ++jj)
        #pragma unroll
        for (int r = 0; r < 16; ++r) acc[jj][r] = 0;

    u64 a0[2], a1[2];                        // [buf]: kw0, kw1

    auto stageB = [&](int gr, int buf) {
        const char* src = Bsrc + (size_t)(gr * 4 + w) * (192 * 1024);
        char* dst = Bdst0 + buf * 12288;
        #pragma unroll
        for (int jj = 0; jj < 3; ++jj)
            __builtin_amdgcn_global_load_lds(
                (const __attribute__((address_space(1))) uint32*)(src + jj * 65536),
                (__attribute__((address_space(3))) uint32*)(dst + jj * 1024),
                16, 0, 0);
    };
    auto loadA = [&](int gr, int buf) {
        a0[buf] = AT[(size_t)(gr * 2 + 0) * M_ROWS];
        a1[buf] = AT[(size_t)(gr * 2 + 1) * M_ROWS];
    };

    // prologue: granule 0 in flight (5 loads per wave)
    stageB(0, 0);
    loadA(0, 0);

    auto iter = [&](int gr, int cur, int pf) {
        stageB(gr + 1, pf);                  // clamp-free: buffers padded
        loadA(gr + 1, pf);
        asm volatile("s_waitcnt vmcnt(5)" ::: "memory");
        __builtin_amdgcn_sched_barrier(0);
        __builtin_amdgcn_s_barrier();        // buf[cur] staged for all waves
        const char* bb = Blds + cur * 12288 + lane * 16;

        // 2-deep rolling B-fragment pipeline (static indices via unroll)
        v4i Bfr[2][3];
        #pragma unroll
        for (int p = 0; p < 2; ++p)
            #pragma unroll
            for (int jj = 0; jj < 3; ++jj)
                Bfr[p][jj] = *(const v4i*)(bb + (p * 3 + jj) * 1024);

        __builtin_amdgcn_s_setprio(1);
        #pragma unroll
        for (int kbl = 0; kbl < 4; ++kbl) {
            v4i B0 = Bfr[kbl & 1][0];
            v4i B1 = Bfr[kbl & 1][1];
            v4i B2 = Bfr[kbl & 1][2];
            if (kbl + 2 < 4) {
                #pragma unroll
                for (int jj = 0; jj < 3; ++jj)
                    Bfr[kbl & 1][jj] =
                        *(const v4i*)(bb + ((kbl + 2) * 3 + jj) * 1024);
            }
            u64 a = (kbl >> 1) ? a1[cur] : a0[cur];
            uint32 dw = (kbl & 1) ? (uint32)(a >> 32) : (uint32)a;
            v4i af = unpack16_bits(dw >> sh16);
            acc[0] = __builtin_amdgcn_mfma_i32_32x32x32_i8(af, B0, acc[0], 0, 0, 0);
            acc[1] = __builtin_amdgcn_mfma_i32_32x32x32_i8(af, B1, acc[1], 0, 0, 0);
            acc[2] = __builtin_amdgcn_mfma_i32_32x32x32_i8(af, B2, acc[2], 0, 0, 0);
        }
        __builtin_amdgcn_s_setprio(0);
        __builtin_amdgcn_s_barrier();        // all waves done with buf[cur]
    };

    for (int gp = 0; gp < NGR; gp += 2) {
        iter(gp + 0, 0, 1);
        iter(gp + 1, 1, 0);
    }

    // ---- epilogue: per-lane exact recombine -> hs (aliases staging LDS) ----
    const double sc = 1.0 / 16777216.0;
    __syncthreads();
    #pragma unroll
    for (int reg = 0; reg < 16; ++reg) {
        int r  = w * 32 + (reg & 3) + 8 * (reg >> 2) + 4 * qd;
        int lo = acc[0][reg] + (acc[1][reg] << 8);
        double d = ((double)lo + 65536.0 * (double)acc[2][reg]) * sc;
        hs[r * 32 + col] = d;
    }
    __syncthreads();

    // ---- LIF: thread = (b_loc = tid>>5, oe = tid&31), single pass ----
    const int b_loc = tid >> 5;
    const int oe    = tid & 31;
    const int o_loc = oe >> 3;
    const int e     = tid & 7;
    const float ge  = g[e];
    const int bg    = mblk * 8 + b_loc;
    const int og    = nblk * 4 + o_loc;
    const int kb_a   = og >> 5;
    const int qd_a   = (og >> 4) & 1;
    const int byte_a = og & 15;

    double v = 0.0;
    float gacc = 0.0f;
    #pragma unroll
    for (int t = 0; t < T_STEPS; ++t) {
        double h  = hs[(b_loc * 16 + t) * 32 + oe];
        double vv = v * 0.95 + h;
        int spk = (vv >= 1.0) ? 1 : 0;
        v = vv - (double)spk;
        float gs = ge * (float)spk;
        gs += __shfl_xor(gs, 1);
        gs += __shfl_xor(gs, 2);
        gs += __shfl_xor(gs, 4);
        gacc += gs;
        int cnt = spk;
        cnt += __shfl_xor(cnt, 1);
        cnt += __shfl_xor(cnt, 2);
        cnt += __shfl_xor(cnt, 4);
        if (e == 0) {
            int mp = bg * 16 + t;
            int lane_a = (mp & 31) + 32 * qd_a;
            Cf[(((size_t)kb_a * MT_ALL + (mp >> 5)) * 64 + lane_a) * 16 + byte_a]
                = (char)cnt;
        }
    }
    if (e == 0) Mean[(size_t)bg * S1 + og] = gacc * 0.0625f;
}

// ---------------------------------------------------------------------------
// Generic fused stage (stages 2/3): R6/R9's proven frag path, 4-limb, block
// 256m x 64n, shuffle recombine epilogue. Unchanged.
// ---------------------------------------------------------------------------
template<int K, int S, int SHIFT, bool WRITEC, int NBLK, int MINW>
__global__ __launch_bounds__(256, MINW) void fused_stage(
    const char* __restrict__ Ap, const char* __restrict__ Bf,
    const float* __restrict__ g, char* __restrict__ Cf,
    float* __restrict__ Mean)
{
    constexpr int KI = K / 64;
    static_assert(KI % 2 == 0, "frag path wants even KI");
    constexpr int NT = S;
    constexpr int NS = NBLK / 8;
    __shared__ double hs[256][16];           // 32 KB

    const int tid  = threadIdx.x;
    const int lane = tid & 63;
    const int w    = tid >> 6;
    const int col  = lane & 31;
    const int qd   = lane >> 5;
    const int wm   = w * 64;

    const int id    = blockIdx.x;
    const int xcd   = id & 7;
    const int inner = id >> 3;
    const int nblk  = xcd * NS + (inner >> 5);
    const int mblk  = inner & 31;
    const int m0    = mblk * 256;

    const int nt0 = nblk * 2;
    const char* Bbase = Bf + ((size_t)nt0 * 64 + lane) * 16;

    v16i acc[2][2];
    #pragma unroll
    for (int i = 0; i < 2; ++i)
        #pragma unroll
        for (int j = 0; j < 2; ++j)
            #pragma unroll
            for (int r = 0; r < 16; ++r) acc[i][j][r] = 0;

    auto loadB = [&](int kb, int jj) -> v4i {
        return *(const v4i*)(Bbase + (size_t)kb * (NT * 1024) + jj * 1024);
    };
    const int mt0 = (m0 + wm) >> 5;
    const char* Abase = Ap + ((size_t)mt0 * 64 + lane) * 16;
    auto loadA = [&](int kb, int ii) -> v4i {
        return *(const v4i*)(Abase + (size_t)kb * (MT_ALL * 1024) + ii * 1024);
    };

    v4i Ab[2][4];
    v4i Bb[2][4];

    #pragma unroll
    for (int ks = 0; ks < 2; ++ks) {
        Ab[0][ks * 2 + 0] = loadA(ks, 0);
        Ab[0][ks * 2 + 1] = loadA(ks, 1);
        #pragma unroll
        for (int jj = 0; jj < 2; ++jj)
            Bb[0][ks * 2 + jj] = loadB(ks, jj);
    }

    auto body = [&](int it, int cur, int pf) {
        const int itp = it + 1;
        #pragma unroll
        for (int ks = 0; ks < 2; ++ks) {
            Ab[pf][ks * 2 + 0] = loadA(itp * 2 + ks, 0);
            Ab[pf][ks * 2 + 1] = loadA(itp * 2 + ks, 1);
            #pragma unroll
            for (int jj = 0; jj < 2; ++jj)
                Bb[pf][ks * 2 + jj] = loadB(itp * 2 + ks, jj);
        }
        #pragma unroll
        for (int ks = 0; ks < 2; ++ks)
            #pragma unroll
            for (int jj = 0; jj < 2; ++jj) {
                acc[0][jj] = __builtin_amdgcn_mfma_i32_32x32x32_i8(Ab[cur][ks*2+0], Bb[cur][ks*2+jj], acc[0][jj], 0,0,0);
                acc[1][jj] = __builtin_amdgcn_mfma_i32_32x32x32_i8(Ab[cur][ks*2+1], Bb[cur][ks*2+jj], acc[1][jj], 0,0,0);
            }
    };
    for (int it = 0; it < KI; it += 2) {
        body(it + 0, 0, 1);
        body(it + 1, 1, 0);
    }

    // ---- limb recombine (exact): int pair-combine then one f64 fma ----
    const double sbase = 1.0 / (double)(1ll << SHIFT);
    #pragma unroll
    for (int j = 0; j < 2; ++j) {
        const int oe = j * 8 + (col >> 2);
        #pragma unroll
        for (int i = 0; i < 2; ++i) {
            #pragma unroll
            for (int reg = 0; reg < 16; ++reg) {
                int a = acc[i][j][reg];
                int s01 = a + (__shfl_xor(a, 1) << 8);
                int s23 = __shfl_xor(s01, 2);
                double d = ((double)s01 + 65536.0 * (double)s23) * sbase;
                if ((col & 3) == 0) {
                    int m = wm + i * 32 + (reg & 3) + 8 * (reg >> 2) + 4 * qd;
                    hs[m][oe] = d;
                }
            }
        }
    }
    __syncthreads();

    const int b_loc  = tid >> 4;
    const int o_loc  = (tid >> 3) & 1;
    const int e      = tid & 7;
    const int oe     = o_loc * 8 + e;
    const float ge   = g[e];
    const int bg = mblk * 16 + b_loc;
    const int og = nblk * 2 + o_loc;

    const int kb_a   = og >> 5;
    const int qd_a   = (og >> 4) & 1;
    const int byte_a = og & 15;

    double v = 0.0;
    float gacc = 0.0f;
    #pragma unroll
    for (int t = 0; t < T_STEPS; ++t) {
        double h  = hs[b_loc * 16 + t][oe];
        double vv = v * 0.95 + h;
        int spk = (vv >= 1.0) ? 1 : 0;
        v = vv - (double)spk;
        float gs = ge * (float)spk;
        gs += __shfl_xor(gs, 1);
        gs += __shfl_xor(gs, 2);
        gs += __shfl_xor(gs, 4);
        gacc += gs;
        if (WRITEC) {
            int cnt = spk;
            cnt += __shfl_xor(cnt, 1);
            cnt += __shfl_xor(cnt, 2);
            cnt += __shfl_xor(cnt, 4);
            if (e == 0) {
                int mp = bg * 16 + t;
                int lane_a = (mp & 31) + 32 * qd_a;
                Cf[(((size_t)kb_a * MT_ALL + (mp >> 5)) * 64 + lane_a) * 16 + byte_a]
                    = (char)cnt;
            }
        }
    }
    if (e == 0) Mean[(size_t)bg * S + og] = gacc * 0.0625f;
}

// ---------------------------------------------------------------------------
// ws layout (bytes), padded for clamp-free prefetch/staging:
//   AbitsT @ 0          : 3 MB  (region 4 MB; A loads reach kw 49 = 3.27 MB)
//   B1f    @ 4194304    : 18 MB 3-limb limb-major (staging reaches kb 99 =
//                          19.6 MB <= region 20.97 MB)
//   B2f    @ 25165824   :  2 MB (region 3 MB >= 2.5 needed)
//   B3f    @ 28311552   :  1 MB (region 2 MB >= 1.3 needed)
//   c1f    @ 30408704   :  2 MB (region 4 MB >= 2.75 needed)
//   c2f    @ 34603008   :  2 MB (region 4 MB)   -> end 38797312 (37 MB)
// ---------------------------------------------------------------------------
extern "C" void kernel_launch(void* const* d_in, const int* in_sizes, int n_in,
                              void* d_out, int out_size, void* d_ws, size_t ws_size,
                              hipStream_t stream) {
    const float* x  = (const float*)d_in[0];
    const float* W1 = (const float*)d_in[1];
    const float* W2 = (const float*)d_in[2];
    const float* W3 = (const float*)d_in[3];
    const float* g1 = (const float*)d_in[4];
    const float* g2 = (const float*)d_in[5];
    const float* g3 = (const float*)d_in[6];
    float* out = (float*)d_out;

    char* ws = (char*)d_ws;
    u64*  AbitsT = (u64*)ws;
    char* B1f    = ws + 4194304ull;
    char* B2f    = ws + 25165824ull;
    char* B3f    = ws + 28311552ull;
    char* c1f    = ws + 30408704ull;
    char* c2f    = ws + 34603008ull;

    dim3 blk(256);

    // --- single precompute dispatch ---
    prep<<<24576 + 4608 + 512 + 256, blk, 0, stream>>>(
        x, W1, W2, W3, AbitsT, B1f, B2f, B3f);

    // --- stage 1: LDS-staged B + 2-deep reg pipeline, 64 mblk * 64 nblk ---
    fused_stage1<<<64 * 64, blk, 0, stream>>>(AbitsT, B1f, g1, c1f, out);

    // --- stages 2/3: proven 4-limb frag path ---
    fused_stage<S1, S2, 35, true,  128, 3><<<32 * 128, blk, 0, stream>>>(
        c1f, B2f, g2, c2f, out + BATCH * S1);
    fused_stage<S2, S3, 35, false, 64, 3><<<32 * 64, blk, 0, stream>>>(
        c2f, B3f, g3, nullptr, out + BATCH * (S1 + S2));
}